// Round 17
// baseline (123.347 us; speedup 1.0000x reference)
//
#include <hip/hip_runtime.h>
#include <hip/hip_fp16.h>

#define IN_CH 256
#define OUT_CH 8
#define LROW 264          // LDS row stride in bf16 elems: 256 + 8 pad

typedef float f32x4  __attribute__((ext_vector_type(4)));
typedef unsigned int u32x4 __attribute__((ext_vector_type(4)));
typedef short short8v __attribute__((ext_vector_type(8)));
typedef short short4v __attribute__((ext_vector_type(4)));

__device__ __forceinline__ short f2bf(float f) {   // f32 -> bf16 (RNE)
    unsigned u = __float_as_uint(f);
    u += 0x7FFFu + ((u >> 16) & 1u);
    return (short)(u >> 16);
}

__device__ __forceinline__ float2 h2f(unsigned w) {  // 2 packed f16 -> 2 f32
    __half2 h = *(__half2*)&w;
    return __half22float2(h);
}

// ---------------------------------------------------------------------------
// Projection v7 EXACT (27.1 us, probe-ladder measured): one wave per 16-row
// tile, ~2 tiles per wave via grid-stride (amortizes W-fragment build),
// mfma_f32_16x16x32_bf16 x8 over K=256, per-wave LDS slice, no barriers.
// ---------------------------------------------------------------------------
__global__ __launch_bounds__(256) void proj_kernel(
    const float* __restrict__ X,
    const float* __restrict__ W1,
    const float* __restrict__ W2,
    __half* __restrict__ P1h,        // [n][8] f16
    __half* __restrict__ P2h,
    int n, int ntiles, int nwaves)
{
    __shared__ short Xs[4][16][LROW];          // 33792 B per block

    const int wv   = threadIdx.x >> 6;
    const int lane = threadIdx.x & 63;
    const int gw   = (blockIdx.x * 256 + threadIdx.x) >> 6;

    const int o  = lane & 15;                  // output column this lane owns
    const int lk = lane >> 4;                  // k-group 0..3

    const float* wrow = (o < 8) ? (W1 + (size_t)o * IN_CH)
                                : (W2 + (size_t)(o - 8) * IN_CH);
    short8v bfr[8];
    #pragma unroll
    for (int kb = 0; kb < 8; ++kb) {
        float4 u = *(const float4*)(wrow + kb * 32 + lk * 8);
        float4 v = *(const float4*)(wrow + kb * 32 + lk * 8 + 4);
        short8v b;
        b[0] = f2bf(u.x); b[1] = f2bf(u.y); b[2] = f2bf(u.z); b[3] = f2bf(u.w);
        b[4] = f2bf(v.x); b[5] = f2bf(v.y); b[6] = f2bf(v.z); b[7] = f2bf(v.w);
        bfr[kb] = b;
    }

    for (int t = gw; t < ntiles; t += nwaves) {
        const int r0 = t * 16;

        #pragma unroll
        for (int i = 0; i < 16; ++i) {
            float4 x = make_float4(0.f, 0.f, 0.f, 0.f);
            if (r0 + i < n)
                x = *(const float4*)(X + (size_t)(r0 + i) * IN_CH + lane * 4);
            short4v s;
            s[0] = f2bf(x.x); s[1] = f2bf(x.y); s[2] = f2bf(x.z); s[3] = f2bf(x.w);
            *(short4v*)&Xs[wv][i][lane * 4] = s;
        }
        // same-wave LDS write->read: compiler inserts lgkmcnt waits

        f32x4 acc = {0.f, 0.f, 0.f, 0.f};
        #pragma unroll
        for (int kb = 0; kb < 8; ++kb) {
            short8v a = *(const short8v*)&Xs[wv][o][kb * 32 + lk * 8];
            acc = __builtin_amdgcn_mfma_f32_16x16x32_bf16(a, bfr[kb], acc, 0, 0, 0);
        }

        #pragma unroll
        for (int r = 0; r < 4; ++r) {
            const int row = r0 + lk * 4 + r;
            if (row < n) {
                __half h = __float2half(acc[r]);
                if (o < 8) P1h[(size_t)row * OUT_CH + o] = h;
                else       P2h[(size_t)row * OUT_CH + (o - 8)] = h;
            }
        }
    }
}

// ---------------------------------------------------------------------------
// Gather g10: random table reads via global_load_lds (per-lane global source
// address, LDS dest = uniform base + lane*16). Data returns TA->LDS directly
// (no VGPR writeback) — tests whether the VGPR-return miss-tracking pool is
// the gather wall. Per wave: 64 edges, 2 gld_lds, vmcnt(0), 2 conflict-free
// ds_read_b128, add, nt stores. Everything else g2-identical.
// ---------------------------------------------------------------------------
typedef const __attribute__((address_space(1))) void gv_t;
typedef __attribute__((address_space(3))) void lv_t;

__global__ __launch_bounds__(256) void gather_kernel(
    const int* __restrict__ e0,
    const int* __restrict__ e1,
    const __half* __restrict__ T1,   // [n*8] f16
    const __half* __restrict__ T2,
    f32x4* __restrict__ outv,        // [E*2] float4
    int E, int n)
{
    __shared__ __align__(16) unsigned lbuf[4][2][256];   // [wave][tbl][64*16B]

    const int wv   = threadIdx.x >> 6;
    const int lane = threadIdx.x & 63;
    const int base = (blockIdx.x * 4 + wv) * 64;         // wave's 64 edges
    if (base >= E) return;

    const unsigned nmax = (unsigned)(n - 1);
    const int e = base + lane;                           // always < E (exact fit)

    unsigned i0 = (unsigned)__builtin_nontemporal_load(e0 + e);
    unsigned i1 = (unsigned)__builtin_nontemporal_load(e1 + e);
    i0 = i0 > nmax ? nmax : i0;
    i1 = i1 > nmax ? nmax : i1;

    // per-lane global src, wave-uniform LDS base (+ lane*16 implicit)
    __builtin_amdgcn_global_load_lds(
        (gv_t*)(T1 + (size_t)i0 * OUT_CH), (lv_t*)&lbuf[wv][0][0], 16, 0, 0);
    __builtin_amdgcn_global_load_lds(
        (gv_t*)(T2 + (size_t)i1 * OUT_CH), (lv_t*)&lbuf[wv][1][0], 16, 0, 0);
    asm volatile("s_waitcnt vmcnt(0)" ::: "memory");

    u32x4 a = *(const u32x4*)&lbuf[wv][0][lane * 4];
    u32x4 b = *(const u32x4*)&lbuf[wv][1][lane * 4];

    float2 s0 = h2f(a[0]), s1 = h2f(a[1]), s2 = h2f(a[2]), s3 = h2f(a[3]);
    float2 t0 = h2f(b[0]), t1 = h2f(b[1]), t2 = h2f(b[2]), t3 = h2f(b[3]);

    f32x4 r0 = { s0.x + t0.x, s0.y + t0.y, s1.x + t1.x, s1.y + t1.y };
    f32x4 r1 = { s2.x + t2.x, s2.y + t2.y, s3.x + t3.x, s3.y + t3.y };

    size_t oi = 2u * (size_t)e;
    __builtin_nontemporal_store(r0, outv + oi);
    __builtin_nontemporal_store(r1, outv + oi + 1);
}

extern "C" void kernel_launch(void* const* d_in, const int* in_sizes, int n_in,
                              void* d_out, int out_size, void* d_ws, size_t ws_size,
                              hipStream_t stream) {
    const float* X    = (const float*)d_in[0];
    const int*   eidx = (const int*)d_in[1];
    const float* W1   = (const float*)d_in[2];
    const float* W2   = (const float*)d_in[3];

    const int n = in_sizes[0] / IN_CH;   // 100000
    const int E = in_sizes[1] / 2;       // 6400000

    __half* P1h = (__half*)d_ws;                    // [n][8] f16 = 1.6 MB
    __half* P2h = P1h + (size_t)n * OUT_CH;         // [n][8] f16 = 1.6 MB

    const int ntiles = (n + 15) / 16;               // 6250
    const int proj_blocks = 768;                    // 3072 waves, ~2 tiles each
    const int nwaves = proj_blocks * 4;
    proj_kernel<<<proj_blocks, 256, 0, stream>>>(
        X, W1, W2, P1h, P2h, n, ntiles, nwaves);

    const int gather_blocks = (E + 255) / 256;      // 25000: 4 waves x 64 edges
    gather_kernel<<<gather_blocks, 256, 0, stream>>>(
        eidx, eidx + E, P1h, P2h, (f32x4*)d_out, E, n);
}